// Round 13
// baseline (492.896 us; speedup 1.0000x reference)
//
#include <hip/hip_runtime.h>
#include <hip/hip_fp16.h>
#include <cmath>

#define H 128
#define GAMMA 0.1f
#define EPS 0.1f
#define NEG 0.01f
#define NGRAPH 256

typedef _Float16 half_t;
typedef _Float16 f16x8 __attribute__((ext_vector_type(8)));
typedef _Float16 f16x4 __attribute__((ext_vector_type(4)));
typedef _Float16 f16x2 __attribute__((ext_vector_type(2)));
typedef float f32x4 __attribute__((ext_vector_type(4)));

__device__ __forceinline__ float fast_tanh(float v) {
    float e = __builtin_amdgcn_exp2f(v * 2.8853900817779268f);
    float r = __builtin_amdgcn_rcpf(e + 1.0f);
    return 1.0f - 2.0f * r;
}

// ---------------- fused (grid-stride): weights->fragment order, x0->f16, deg=0
__global__ __launch_bounds__(256) void prep_cast_zero(
        const float* __restrict__ W, const float* __restrict__ lin_w,
        half_t* __restrict__ WtTf, const float* __restrict__ x,
        half_t* __restrict__ xh, int n4, int* __restrict__ deg, int N) {
    int stride = gridDim.x * 256;
    int tot = max(n4, max(32768, N));
    for (int i = blockIdx.x * 256 + threadIdx.x; i < tot; i += stride) {
        if (i < n4) {
            float4 v = *(const float4*)(x + (size_t)i * 4);
            half_t* o = xh + (size_t)i * 4;
            o[0] = (half_t)v.x; o[1] = (half_t)v.y; o[2] = (half_t)v.z; o[3] = (half_t)v.w;
        }
        if (i < 32768) {
            int t = i & 7;
            int lane = (i >> 3) & 63;
            int ct = (i >> 9) & 7;
            int s = i >> 12;
            int q = lane >> 4, m = lane & 15;
            int j = ct * 16 + m;
            int k = s * 32 + q * 8 + t;
            float v;
            if (k < H) v = W[j * H + k] - W[k * H + j] - (j == k ? GAMMA : 0.f);
            else       v = lin_w[j * H + (k - H)];
            WtTf[i] = (half_t)v;
        }
        if (i < N) deg[i] = 0;
    }
}

// ---------------- CSR build (grid-stride)
__global__ __launch_bounds__(256) void count_kernel(const int* __restrict__ dst,
                                                    int* __restrict__ deg, int E) {
    int stride = gridDim.x * 256;
    for (int e = blockIdx.x * 256 + threadIdx.x; e < E; e += stride)
        atomicAdd(&deg[dst[e]], 1);
}

#define SCHUNK 2048
__global__ __launch_bounds__(256) void scan_part(const int* __restrict__ deg,
                                                 int* __restrict__ partials, int N) {
    __shared__ int red[256];
    int t = threadIdx.x, b = blockIdx.x;
    int base = b * SCHUNK + t * 8;
    int s = 0;
#pragma unroll
    for (int i = 0; i < 8; ++i) { int idx = base + i; if (idx < N) s += deg[idx]; }
    red[t] = s;
    __syncthreads();
    for (int off = 128; off > 0; off >>= 1) {
        if (t < off) red[t] += red[t + off];
        __syncthreads();
    }
    if (t == 0) partials[b] = red[0];
}

__global__ void scan_mid(const int* __restrict__ partials, int* __restrict__ blkoff, int nblk) {
    int lane = threadIdx.x;   // 64 threads
    int p = (lane < nblk) ? partials[lane] : 0;
    int v = p;
    for (int off = 1; off < 64; off <<= 1) {
        int u = __shfl_up(v, off);
        if (lane >= off) v += u;
    }
    if (lane < nblk) blkoff[lane] = v - p;
}

__global__ __launch_bounds__(256) void scan_final(const int* __restrict__ deg,
        const int* __restrict__ blkoff, int* __restrict__ row_start,
        int* __restrict__ cursor, int N, int E) {
    __shared__ int red[256];
    int t = threadIdx.x, b = blockIdx.x;
    int base = b * SCHUNK + t * 8;
    int v[8]; int s = 0;
#pragma unroll
    for (int i = 0; i < 8; ++i) { int idx = base + i; v[i] = (idx < N) ? deg[idx] : 0; s += v[i]; }
    red[t] = s;
    __syncthreads();
    for (int off = 1; off < 256; off <<= 1) {
        int u = (t >= off) ? red[t - off] : 0;
        __syncthreads();
        red[t] += u;
        __syncthreads();
    }
    int run = blkoff[b] + red[t] - s;
#pragma unroll
    for (int i = 0; i < 8; ++i) {
        int idx = base + i;
        if (idx < N) { row_start[idx] = run; cursor[idx] = run; run += v[i]; }
    }
    if (b == 0 && t == 0) row_start[N] = E;
}

__global__ __launch_bounds__(256) void fill_kernel(const int* __restrict__ src,
        const int* __restrict__ dst, int* __restrict__ cursor,
        int* __restrict__ csr_src, int E) {
    int stride = gridDim.x * 256;
    for (int e = blockIdx.x * 256 + threadIdx.x; e < E; e += stride) {
        int p = atomicAdd(&cursor[dst[e]], 1);
        csr_src[p] = src[e];
    }
}

// ---------------- gather aggregation (R12 body) + DIAGNOSTIC rep loop.
// reps>1 repeats the full idempotent pass; an opaque asm barrier on the rep
// counter prevents hoisting/elimination, so dispatch duration = reps * single.
__global__ __launch_bounds__(256) void gather_agg(const half_t* __restrict__ xh,
        const int* __restrict__ row_start, const int* __restrict__ csr_src,
        half_t* __restrict__ xaggh, int N, int reps) {
    int wid0 = __builtin_amdgcn_readfirstlane(blockIdx.x * 4 + (threadIdx.x >> 6));
    int nwaves = gridDim.x * 4;
    int lane = threadIdx.x & 63;
    for (int rep = 0; rep < reps; ++rep) {
        int r2 = rep;
        asm volatile("" : "+v"(r2));             // opaque: defeat rep hoisting
        const half_t* xp = xh + (r2 - rep);      // actually == xh
        for (int node = wid0; node < N; node += nwaves) {
            int begin = row_start[node];
            int end   = row_start[node + 1];
            f16x2 accA = (f16x2){(half_t)0.f, (half_t)0.f};
            f16x2 accB = (f16x2){(half_t)0.f, (half_t)0.f};
            for (int base = begin; base < end; base += 64) {
                int cnt = min(64, end - base);
                int myidx = csr_src[base + min(lane, cnt - 1)];
                int j = 0;
                for (; j + 7 < cnt; j += 8) {
                    int s0 = __builtin_amdgcn_readlane(myidx, j + 0);
                    int s1 = __builtin_amdgcn_readlane(myidx, j + 1);
                    int s2 = __builtin_amdgcn_readlane(myidx, j + 2);
                    int s3 = __builtin_amdgcn_readlane(myidx, j + 3);
                    int s4 = __builtin_amdgcn_readlane(myidx, j + 4);
                    int s5 = __builtin_amdgcn_readlane(myidx, j + 5);
                    int s6 = __builtin_amdgcn_readlane(myidx, j + 6);
                    int s7 = __builtin_amdgcn_readlane(myidx, j + 7);
                    f16x2 v0 = *(const f16x2*)(xp + (size_t)s0 * H + lane * 2);
                    f16x2 v1 = *(const f16x2*)(xp + (size_t)s1 * H + lane * 2);
                    f16x2 v2 = *(const f16x2*)(xp + (size_t)s2 * H + lane * 2);
                    f16x2 v3 = *(const f16x2*)(xp + (size_t)s3 * H + lane * 2);
                    f16x2 v4 = *(const f16x2*)(xp + (size_t)s4 * H + lane * 2);
                    f16x2 v5 = *(const f16x2*)(xp + (size_t)s5 * H + lane * 2);
                    f16x2 v6 = *(const f16x2*)(xp + (size_t)s6 * H + lane * 2);
                    f16x2 v7 = *(const f16x2*)(xp + (size_t)s7 * H + lane * 2);
                    accA += v0; accB += v1; accA += v2; accB += v3;
                    accA += v4; accB += v5; accA += v6; accB += v7;
                }
                if (cnt - j >= 4) {
                    int s0 = __builtin_amdgcn_readlane(myidx, j + 0);
                    int s1 = __builtin_amdgcn_readlane(myidx, j + 1);
                    int s2 = __builtin_amdgcn_readlane(myidx, j + 2);
                    int s3 = __builtin_amdgcn_readlane(myidx, j + 3);
                    f16x2 v0 = *(const f16x2*)(xp + (size_t)s0 * H + lane * 2);
                    f16x2 v1 = *(const f16x2*)(xp + (size_t)s1 * H + lane * 2);
                    f16x2 v2 = *(const f16x2*)(xp + (size_t)s2 * H + lane * 2);
                    f16x2 v3 = *(const f16x2*)(xp + (size_t)s3 * H + lane * 2);
                    accA += v0; accB += v1; accA += v2; accB += v3;
                    j += 4;
                }
                int rem = cnt - j;
                if (rem > 0) {
                    int s0 = __builtin_amdgcn_readlane(myidx, j);
                    int s1 = __builtin_amdgcn_readlane(myidx, min(j + 1, cnt - 1));
                    int s2 = __builtin_amdgcn_readlane(myidx, min(j + 2, cnt - 1));
                    f16x2 v0 = *(const f16x2*)(xp + (size_t)s0 * H + lane * 2);
                    f16x2 v1 = *(const f16x2*)(xp + (size_t)s1 * H + lane * 2);
                    f16x2 v2 = *(const f16x2*)(xp + (size_t)s2 * H + lane * 2);
                    accA += v0;
                    if (rem > 1) accB += v1;
                    if (rem > 2) accA += v2;
                }
            }
            f16x2 o = accA + accB;
            *(f16x2*)(xaggh + (size_t)node * H + lane * 2) = o;
        }
    }
}

// ---------------- conv+update via f16 MFMA (R12 body) + DIAGNOSTIC rep loop.
#define CROWS 128
__global__ __launch_bounds__(256) void conv_mfma(
        const half_t* __restrict__ xh, const half_t* __restrict__ xaggh,
        const half_t* __restrict__ WtTf, const float* __restrict__ bias,
        half_t* __restrict__ xhout, int N, int reps) {
    int tid = threadIdx.x;
    int wave = tid >> 6, lane = tid & 63;
    int q = lane >> 4, m = lane & 15;
    int n0 = blockIdx.x * CROWS + wave * 32;

    for (int rep = 0; rep < reps; ++rep) {
        int r2 = rep;
        asm volatile("" : "+v"(r2));             // opaque: defeat rep hoisting
        const half_t* xp = xh + (r2 - rep);      // actually == xh

        f32x4 acc[2][8];
#pragma unroll
        for (int rt = 0; rt < 2; ++rt)
#pragma unroll
            for (int ct = 0; ct < 8; ++ct) acc[rt][ct] = (f32x4){0.f, 0.f, 0.f, 0.f};

#pragma unroll
        for (int s = 0; s < 8; ++s) {
            f16x8 afrag[2];
#pragma unroll
            for (int rt = 0; rt < 2; ++rt) {
                int row = min(n0 + rt * 16 + m, N - 1);
                afrag[rt] = (s < 4)
                    ? *(const f16x8*)(xp    + (size_t)row * H + s * 32 + q * 8)
                    : *(const f16x8*)(xaggh + (size_t)row * H + (s - 4) * 32 + q * 8);
            }
#pragma unroll
            for (int ct = 0; ct < 8; ++ct) {
                f16x8 bfrag = *(const f16x8*)(WtTf + ((s * 8 + ct) * 64 + lane) * 8);
                acc[0][ct] = __builtin_amdgcn_mfma_f32_16x16x32_f16(afrag[0], bfrag, acc[0][ct], 0, 0, 0);
                acc[1][ct] = __builtin_amdgcn_mfma_f32_16x16x32_f16(afrag[1], bfrag, acc[1][ct], 0, 0, 0);
            }
        }

#pragma unroll
        for (int rt = 0; rt < 2; ++rt) {
#pragma unroll
            for (int r = 0; r < 4; ++r) {
                int row = n0 + rt * 16 + q * 4 + r;
                if (row < N) {
#pragma unroll
                    for (int ct = 0; ct < 8; ++ct) {
                        int col = ct * 16 + m;
                        float c = acc[rt][ct][r] + bias[col];
                        float o = (float)xp[(size_t)row * H + col] + EPS * fast_tanh(c);
                        xhout[(size_t)row * H + col] = (half_t)o;
                    }
                }
            }
        }
    }
}

// ---------------- fused triple pooling + 2-layer MLP (one block per graph)
__global__ __launch_bounds__(1024) void pool_mlp(const half_t* __restrict__ x,
        const int* __restrict__ batch,
        const float* __restrict__ l1_w, const float* __restrict__ l1_b,
        const float* __restrict__ l2_w, const float* __restrict__ l2_b,
        float* __restrict__ out, int N) {
    __shared__ float ssum[8][128];
    __shared__ float smax[8][128];
    __shared__ __align__(16) float sp[384];
    __shared__ __align__(16) float sh[192];
    int g = blockIdx.x, t = threadIdx.x;
    int feat = t & 127, slot = t >> 7;   // 8 slots
    int lo = 0, hi = N;
    while (lo < hi) { int mid = (lo + hi) >> 1; if (batch[mid] < g) lo = mid + 1; else hi = mid; }
    int start = lo;
    hi = N;
    while (lo < hi) { int mid = (lo + hi) >> 1; if (batch[mid] < g + 1) lo = mid + 1; else hi = mid; }
    int end = lo;
    float sum = 0.f, mx = -INFINITY;
    for (int n = start + slot; n < end; n += 8) {
        float v = (float)x[(size_t)n * H + feat];
        sum += v;
        mx = fmaxf(mx, v);
    }
    ssum[slot][feat] = sum;
    smax[slot][feat] = mx;
    __syncthreads();
    if (t < 128) {
        float s = 0.f, m = -INFINITY;
#pragma unroll
        for (int k = 0; k < 8; ++k) { s += ssum[k][t]; m = fmaxf(m, smax[k][t]); }
        int cnt = end - start;
        sp[t] = s;
        sp[128 + t] = (cnt > 0) ? m : 0.f;
        sp[256 + t] = s / (float)(cnt > 0 ? cnt : 1);
    }
    __syncthreads();
    if (t < 192) {
        float acc = l1_b[t];
        const float* wr = l1_w + (size_t)t * 384;
        for (int k = 0; k < 384; k += 4) {
            float4 w = *(const float4*)(wr + k);
            float4 p = *(const float4*)(sp + k);
            acc += w.x * p.x + w.y * p.y + w.z * p.z + w.w * p.w;
        }
        sh[t] = acc > 0.f ? acc : NEG * acc;
    }
    __syncthreads();
    if (t < 64) {
        float acc = l2_b[t];
        const float* wr = l2_w + (size_t)t * 192;
        for (int k = 0; k < 192; k += 4) {
            float4 w = *(const float4*)(wr + k);
            float4 p = *(const float4*)(sh + k);
            acc += w.x * p.x + w.y * p.y + w.z * p.z + w.w * p.w;
        }
        out[g * 64 + t] = acc > 0.f ? acc : NEG * acc;
    }
}

extern "C" void kernel_launch(void* const* d_in, const int* in_sizes, int n_in,
                              void* d_out, int out_size, void* d_ws, size_t ws_size,
                              hipStream_t stream) {
    const float* x0    = (const float*)d_in[0];
    const int*   edge  = (const int*)d_in[1];
    const int*   batch = (const int*)d_in[2];
    const float* W     = (const float*)d_in[3];
    const float* bias  = (const float*)d_in[4];
    const float* lin_w = (const float*)d_in[5];
    const float* l1_w  = (const float*)d_in[6];
    const float* l1_b  = (const float*)d_in[7];
    const float* l2_w  = (const float*)d_in[8];
    const float* l2_b  = (const float*)d_in[9];
    float* out = (float*)d_out;

    int N = in_sizes[0] / H;
    int E = in_sizes[1] / 2;
    const int* src = edge;
    const int* dst = edge + E;

    size_t nh = (size_t)N * H;
    half_t* xhA    = (half_t*)d_ws;
    half_t* xhB    = xhA + nh;
    half_t* xaggh  = xhB + nh;
    half_t* WtTf   = xaggh + nh;              // 32768 halfs
    int* deg       = (int*)(WtTf + 32768);
    int* row_start = deg + N;                 // N+1
    int* cursor    = row_start + N + 1;
    int* csr_src   = cursor + N;              // E
    int* partials  = csr_src + E;             // 64
    int* blkoff    = partials + 64;           // 64

    int n4 = (int)(nh / 4);
    prep_cast_zero<<<1024, 256, 0, stream>>>(W, lin_w, WtTf, x0, xhA, n4, deg, N);

    count_kernel<<<1024, 256, 0, stream>>>(dst, deg, E);
    int nblk = (N + SCHUNK - 1) / SCHUNK;
    scan_part<<<nblk, 256, 0, stream>>>(deg, partials, N);
    scan_mid<<<1, 64, 0, stream>>>(partials, blkoff, nblk);
    scan_final<<<nblk, 256, 0, stream>>>(deg, blkoff, row_start, cursor, N, E);
    fill_kernel<<<1024, 256, 0, stream>>>(src, dst, cursor, csr_src, E);

    const half_t* xcur_h = xhA;
    int nblocks = (N + CROWS - 1) / CROWS;
    for (int it = 0; it < 5; ++it) {
        int reps = (it == 0) ? 3 : 1;   // DIAGNOSTIC: make iter-0 phases visible
        gather_agg<<<2048, 256, 0, stream>>>(xcur_h, row_start, csr_src, xaggh, N, reps);
        half_t* xnext_h = (it & 1) ? xhA : xhB;
        conv_mfma<<<nblocks, 256, 0, stream>>>(xcur_h, xaggh, WtTf, bias, xnext_h, N, reps);
        xcur_h = xnext_h;
    }

    pool_mlp<<<NGRAPH, 1024, 0, stream>>>(xcur_h, batch, l1_w, l1_b, l2_w, l2_b, out, N);
}

// Round 14
// 372.719 us; speedup vs baseline: 1.3224x; 1.3224x over previous
//
#include <hip/hip_runtime.h>
#include <hip/hip_fp16.h>
#include <cmath>

#define H 128
#define GAMMA 0.1f
#define EPS 0.1f
#define NEG 0.01f
#define NGRAPH 256

typedef _Float16 half_t;
typedef _Float16 f16x8 __attribute__((ext_vector_type(8)));
typedef _Float16 f16x4 __attribute__((ext_vector_type(4)));
typedef _Float16 f16x2 __attribute__((ext_vector_type(2)));
typedef float f32x4 __attribute__((ext_vector_type(4)));

__device__ __forceinline__ float fast_tanh(float v) {
    float e = __builtin_amdgcn_exp2f(v * 2.8853900817779268f);
    float r = __builtin_amdgcn_rcpf(e + 1.0f);
    return 1.0f - 2.0f * r;
}

// ---------------- fused (grid-stride): weights->fragment order, x0->f16, deg=0
// B-fragment order with PERMUTED output cols: tile ct covers cols j = m*8+ct
// (m = lane&15) so the MFMA C-layout gives each lane 8 consecutive cols ->
// vectorized epilogue. WtTf[((s*8+ct)*64+lane)*8+t] = M[j][k],
// j=(lane&15)*8+ct, k=s*32+(lane>>4)*8+t.
// M[j][k] = (k<H) ? W[j][k]-W[k][j]-gamma*delta(j,k) : lin_w[j][k-H]
__global__ __launch_bounds__(256) void prep_cast_zero(
        const float* __restrict__ W, const float* __restrict__ lin_w,
        half_t* __restrict__ WtTf, const float* __restrict__ x,
        half_t* __restrict__ xh, int n4, int* __restrict__ deg, int N) {
    int stride = gridDim.x * 256;
    int tot = max(n4, max(32768, N));
    for (int i = blockIdx.x * 256 + threadIdx.x; i < tot; i += stride) {
        if (i < n4) {
            float4 v = *(const float4*)(x + (size_t)i * 4);
            half_t* o = xh + (size_t)i * 4;
            o[0] = (half_t)v.x; o[1] = (half_t)v.y; o[2] = (half_t)v.z; o[3] = (half_t)v.w;
        }
        if (i < 32768) {
            int t = i & 7;
            int lane = (i >> 3) & 63;
            int ct = (i >> 9) & 7;
            int s = i >> 12;
            int q = lane >> 4, m = lane & 15;
            int j = m * 8 + ct;                  // permuted col mapping
            int k = s * 32 + q * 8 + t;
            float v;
            if (k < H) v = W[j * H + k] - W[k * H + j] - (j == k ? GAMMA : 0.f);
            else       v = lin_w[j * H + (k - H)];
            WtTf[i] = (half_t)v;
        }
        if (i < N) deg[i] = 0;
    }
}

// ---------------- CSR build (grid-stride)
__global__ __launch_bounds__(256) void count_kernel(const int* __restrict__ dst,
                                                    int* __restrict__ deg, int E) {
    int stride = gridDim.x * 256;
    for (int e = blockIdx.x * 256 + threadIdx.x; e < E; e += stride)
        atomicAdd(&deg[dst[e]], 1);
}

#define SCHUNK 2048
__global__ __launch_bounds__(256) void scan_part(const int* __restrict__ deg,
                                                 int* __restrict__ partials, int N) {
    __shared__ int red[256];
    int t = threadIdx.x, b = blockIdx.x;
    int base = b * SCHUNK + t * 8;
    int s = 0;
#pragma unroll
    for (int i = 0; i < 8; ++i) { int idx = base + i; if (idx < N) s += deg[idx]; }
    red[t] = s;
    __syncthreads();
    for (int off = 128; off > 0; off >>= 1) {
        if (t < off) red[t] += red[t + off];
        __syncthreads();
    }
    if (t == 0) partials[b] = red[0];
}

__global__ void scan_mid(const int* __restrict__ partials, int* __restrict__ blkoff, int nblk) {
    int lane = threadIdx.x;   // 64 threads
    int p = (lane < nblk) ? partials[lane] : 0;
    int v = p;
    for (int off = 1; off < 64; off <<= 1) {
        int u = __shfl_up(v, off);
        if (lane >= off) v += u;
    }
    if (lane < nblk) blkoff[lane] = v - p;
}

__global__ __launch_bounds__(256) void scan_final(const int* __restrict__ deg,
        const int* __restrict__ blkoff, int* __restrict__ row_start,
        int* __restrict__ cursor, int N, int E) {
    __shared__ int red[256];
    int t = threadIdx.x, b = blockIdx.x;
    int base = b * SCHUNK + t * 8;
    int v[8]; int s = 0;
#pragma unroll
    for (int i = 0; i < 8; ++i) { int idx = base + i; v[i] = (idx < N) ? deg[idx] : 0; s += v[i]; }
    red[t] = s;
    __syncthreads();
    for (int off = 1; off < 256; off <<= 1) {
        int u = (t >= off) ? red[t - off] : 0;
        __syncthreads();
        red[t] += u;
        __syncthreads();
    }
    int run = blkoff[b] + red[t] - s;
#pragma unroll
    for (int i = 0; i < 8; ++i) {
        int idx = base + i;
        if (idx < N) { row_start[idx] = run; cursor[idx] = run; run += v[i]; }
    }
    if (b == 0 && t == 0) row_start[N] = E;
}

__global__ __launch_bounds__(256) void fill_kernel(const int* __restrict__ src,
        const int* __restrict__ dst, int* __restrict__ cursor,
        int* __restrict__ csr_src, int E) {
    int stride = gridDim.x * 256;
    for (int e = blockIdx.x * 256 + threadIdx.x; e < E; e += stride) {
        int p = atomicAdd(&cursor[dst[e]], 1);
        csr_src[p] = src[e];
    }
}

// ---------------- gather aggregation (R12 body, reps removed)
__global__ __launch_bounds__(256) void gather_agg(const half_t* __restrict__ xh,
        const int* __restrict__ row_start, const int* __restrict__ csr_src,
        half_t* __restrict__ xaggh, int N) {
    int wid = __builtin_amdgcn_readfirstlane(blockIdx.x * 4 + (threadIdx.x >> 6));
    int nwaves = gridDim.x * 4;
    int lane = threadIdx.x & 63;
    for (int node = wid; node < N; node += nwaves) {
        int begin = row_start[node];
        int end   = row_start[node + 1];
        f16x2 accA = (f16x2){(half_t)0.f, (half_t)0.f};
        f16x2 accB = (f16x2){(half_t)0.f, (half_t)0.f};
        for (int base = begin; base < end; base += 64) {
            int cnt = min(64, end - base);
            int myidx = csr_src[base + min(lane, cnt - 1)];
            int j = 0;
            for (; j + 7 < cnt; j += 8) {
                int s0 = __builtin_amdgcn_readlane(myidx, j + 0);
                int s1 = __builtin_amdgcn_readlane(myidx, j + 1);
                int s2 = __builtin_amdgcn_readlane(myidx, j + 2);
                int s3 = __builtin_amdgcn_readlane(myidx, j + 3);
                int s4 = __builtin_amdgcn_readlane(myidx, j + 4);
                int s5 = __builtin_amdgcn_readlane(myidx, j + 5);
                int s6 = __builtin_amdgcn_readlane(myidx, j + 6);
                int s7 = __builtin_amdgcn_readlane(myidx, j + 7);
                f16x2 v0 = *(const f16x2*)(xh + (size_t)s0 * H + lane * 2);
                f16x2 v1 = *(const f16x2*)(xh + (size_t)s1 * H + lane * 2);
                f16x2 v2 = *(const f16x2*)(xh + (size_t)s2 * H + lane * 2);
                f16x2 v3 = *(const f16x2*)(xh + (size_t)s3 * H + lane * 2);
                f16x2 v4 = *(const f16x2*)(xh + (size_t)s4 * H + lane * 2);
                f16x2 v5 = *(const f16x2*)(xh + (size_t)s5 * H + lane * 2);
                f16x2 v6 = *(const f16x2*)(xh + (size_t)s6 * H + lane * 2);
                f16x2 v7 = *(const f16x2*)(xh + (size_t)s7 * H + lane * 2);
                accA += v0; accB += v1; accA += v2; accB += v3;
                accA += v4; accB += v5; accA += v6; accB += v7;
            }
            if (cnt - j >= 4) {
                int s0 = __builtin_amdgcn_readlane(myidx, j + 0);
                int s1 = __builtin_amdgcn_readlane(myidx, j + 1);
                int s2 = __builtin_amdgcn_readlane(myidx, j + 2);
                int s3 = __builtin_amdgcn_readlane(myidx, j + 3);
                f16x2 v0 = *(const f16x2*)(xh + (size_t)s0 * H + lane * 2);
                f16x2 v1 = *(const f16x2*)(xh + (size_t)s1 * H + lane * 2);
                f16x2 v2 = *(const f16x2*)(xh + (size_t)s2 * H + lane * 2);
                f16x2 v3 = *(const f16x2*)(xh + (size_t)s3 * H + lane * 2);
                accA += v0; accB += v1; accA += v2; accB += v3;
                j += 4;
            }
            int rem = cnt - j;
            if (rem > 0) {
                int s0 = __builtin_amdgcn_readlane(myidx, j);
                int s1 = __builtin_amdgcn_readlane(myidx, min(j + 1, cnt - 1));
                int s2 = __builtin_amdgcn_readlane(myidx, min(j + 2, cnt - 1));
                f16x2 v0 = *(const f16x2*)(xh + (size_t)s0 * H + lane * 2);
                f16x2 v1 = *(const f16x2*)(xh + (size_t)s1 * H + lane * 2);
                f16x2 v2 = *(const f16x2*)(xh + (size_t)s2 * H + lane * 2);
                accA += v0;
                if (rem > 1) accB += v1;
                if (rem > 2) accA += v2;
            }
        }
        f16x2 o = accA + accB;
        *(f16x2*)(xaggh + (size_t)node * H + lane * 2) = o;
    }
}

// ---------------- conv+update v2: 4 waves x 16 rows = 64 rows/block (782
// blocks), acc[8] only (low VGPR -> high occupancy). Permuted B layout gives
// lane 8 consecutive output cols -> f16x8 vector residual load + store.
#define CROWS 64
__global__ __launch_bounds__(256) void conv_mfma(
        const half_t* __restrict__ xh, const half_t* __restrict__ xaggh,
        const half_t* __restrict__ WtTf, const float* __restrict__ bias,
        half_t* __restrict__ xhout, int N) {
    int tid = threadIdx.x;
    int wave = tid >> 6, lane = tid & 63;
    int q = lane >> 4, m = lane & 15;
    int n0 = blockIdx.x * CROWS + wave * 16;

    f32x4 acc[8];
#pragma unroll
    for (int ct = 0; ct < 8; ++ct) acc[ct] = (f32x4){0.f, 0.f, 0.f, 0.f};

    int arow = min(n0 + m, N - 1);
#pragma unroll
    for (int s = 0; s < 8; ++s) {
        f16x8 afrag = (s < 4)
            ? *(const f16x8*)(xh    + (size_t)arow * H + s * 32 + q * 8)
            : *(const f16x8*)(xaggh + (size_t)arow * H + (s - 4) * 32 + q * 8);
#pragma unroll
        for (int ct = 0; ct < 8; ++ct) {
            f16x8 bfrag = *(const f16x8*)(WtTf + ((s * 8 + ct) * 64 + lane) * 8);
            acc[ct] = __builtin_amdgcn_mfma_f32_16x16x32_f16(afrag, bfrag, acc[ct], 0, 0, 0);
        }
    }

    // epilogue: lane (q,m), reg r -> row n0+q*4+r, cols m*8 .. m*8+7
    float4 b0 = *(const float4*)(bias + m * 8);
    float4 b1 = *(const float4*)(bias + m * 8 + 4);
    float bb[8] = {b0.x, b0.y, b0.z, b0.w, b1.x, b1.y, b1.z, b1.w};
#pragma unroll
    for (int r = 0; r < 4; ++r) {
        int row = n0 + q * 4 + r;
        if (row < N) {
            f16x8 xr = *(const f16x8*)(xh + (size_t)row * H + m * 8);
            f16x8 o;
#pragma unroll
            for (int ct = 0; ct < 8; ++ct) {
                float c = acc[ct][r] + bb[ct];
                o[ct] = (half_t)((float)xr[ct] + EPS * fast_tanh(c));
            }
            *(f16x8*)(xhout + (size_t)row * H + m * 8) = o;
        }
    }
}

// ---------------- fused triple pooling + 2-layer MLP (one block per graph)
__global__ __launch_bounds__(1024) void pool_mlp(const half_t* __restrict__ x,
        const int* __restrict__ batch,
        const float* __restrict__ l1_w, const float* __restrict__ l1_b,
        const float* __restrict__ l2_w, const float* __restrict__ l2_b,
        float* __restrict__ out, int N) {
    __shared__ float ssum[8][128];
    __shared__ float smax[8][128];
    __shared__ __align__(16) float sp[384];
    __shared__ __align__(16) float sh[192];
    int g = blockIdx.x, t = threadIdx.x;
    int feat = t & 127, slot = t >> 7;   // 8 slots
    int lo = 0, hi = N;
    while (lo < hi) { int mid = (lo + hi) >> 1; if (batch[mid] < g) lo = mid + 1; else hi = mid; }
    int start = lo;
    hi = N;
    while (lo < hi) { int mid = (lo + hi) >> 1; if (batch[mid] < g + 1) lo = mid + 1; else hi = mid; }
    int end = lo;
    float sum = 0.f, mx = -INFINITY;
    for (int n = start + slot; n < end; n += 8) {
        float v = (float)x[(size_t)n * H + feat];
        sum += v;
        mx = fmaxf(mx, v);
    }
    ssum[slot][feat] = sum;
    smax[slot][feat] = mx;
    __syncthreads();
    if (t < 128) {
        float s = 0.f, m = -INFINITY;
#pragma unroll
        for (int k = 0; k < 8; ++k) { s += ssum[k][t]; m = fmaxf(m, smax[k][t]); }
        int cnt = end - start;
        sp[t] = s;
        sp[128 + t] = (cnt > 0) ? m : 0.f;
        sp[256 + t] = s / (float)(cnt > 0 ? cnt : 1);
    }
    __syncthreads();
    if (t < 192) {
        float acc = l1_b[t];
        const float* wr = l1_w + (size_t)t * 384;
        for (int k = 0; k < 384; k += 4) {
            float4 w = *(const float4*)(wr + k);
            float4 p = *(const float4*)(sp + k);
            acc += w.x * p.x + w.y * p.y + w.z * p.z + w.w * p.w;
        }
        sh[t] = acc > 0.f ? acc : NEG * acc;
    }
    __syncthreads();
    if (t < 64) {
        float acc = l2_b[t];
        const float* wr = l2_w + (size_t)t * 192;
        for (int k = 0; k < 192; k += 4) {
            float4 w = *(const float4*)(wr + k);
            float4 p = *(const float4*)(sh + k);
            acc += w.x * p.x + w.y * p.y + w.z * p.z + w.w * p.w;
        }
        out[g * 64 + t] = acc > 0.f ? acc : NEG * acc;
    }
}

extern "C" void kernel_launch(void* const* d_in, const int* in_sizes, int n_in,
                              void* d_out, int out_size, void* d_ws, size_t ws_size,
                              hipStream_t stream) {
    const float* x0    = (const float*)d_in[0];
    const int*   edge  = (const int*)d_in[1];
    const int*   batch = (const int*)d_in[2];
    const float* W     = (const float*)d_in[3];
    const float* bias  = (const float*)d_in[4];
    const float* lin_w = (const float*)d_in[5];
    const float* l1_w  = (const float*)d_in[6];
    const float* l1_b  = (const float*)d_in[7];
    const float* l2_w  = (const float*)d_in[8];
    const float* l2_b  = (const float*)d_in[9];
    float* out = (float*)d_out;

    int N = in_sizes[0] / H;
    int E = in_sizes[1] / 2;
    const int* src = edge;
    const int* dst = edge + E;

    size_t nh = (size_t)N * H;
    half_t* xhA    = (half_t*)d_ws;
    half_t* xhB    = xhA + nh;
    half_t* xaggh  = xhB + nh;
    half_t* WtTf   = xaggh + nh;              // 32768 halfs
    int* deg       = (int*)(WtTf + 32768);
    int* row_start = deg + N;                 // N+1
    int* cursor    = row_start + N + 1;
    int* csr_src   = cursor + N;              // E
    int* partials  = csr_src + E;             // 64
    int* blkoff    = partials + 64;           // 64

    int n4 = (int)(nh / 4);
    prep_cast_zero<<<1024, 256, 0, stream>>>(W, lin_w, WtTf, x0, xhA, n4, deg, N);

    count_kernel<<<1024, 256, 0, stream>>>(dst, deg, E);
    int nblk = (N + SCHUNK - 1) / SCHUNK;
    scan_part<<<nblk, 256, 0, stream>>>(deg, partials, N);
    scan_mid<<<1, 64, 0, stream>>>(partials, blkoff, nblk);
    scan_final<<<nblk, 256, 0, stream>>>(deg, blkoff, row_start, cursor, N, E);
    fill_kernel<<<1024, 256, 0, stream>>>(src, dst, cursor, csr_src, E);

    const half_t* xcur_h = xhA;
    int nblocks = (N + CROWS - 1) / CROWS;
    for (int it = 0; it < 5; ++it) {
        gather_agg<<<2048, 256, 0, stream>>>(xcur_h, row_start, csr_src, xaggh, N);
        half_t* xnext_h = (it & 1) ? xhA : xhB;
        conv_mfma<<<nblocks, 256, 0, stream>>>(xcur_h, xaggh, WtTf, bias, xnext_h, N);
        xcur_h = xnext_h;
    }

    pool_mlp<<<NGRAPH, 1024, 0, stream>>>(xcur_h, batch, l1_w, l1_b, l2_w, l2_b, out, N);
}